// Round 6
// baseline (263.343 us; speedup 1.0000x reference)
//
#include <hip/hip_runtime.h>

typedef float floatx4 __attribute__((ext_vector_type(4)));
typedef __bf16 bf16x8 __attribute__((ext_vector_type(8)));
typedef __bf16 bf16x4 __attribute__((ext_vector_type(4)));

#define MFMA16 __builtin_amdgcn_mfma_f32_16x16x32_bf16

typedef const __attribute__((address_space(1))) void* gas_t;
typedef __attribute__((address_space(3))) void* las_t;
#define GLD16(g, l) __builtin_amdgcn_global_load_lds((gas_t)(g), (las_t)(l), 16, 0, 0)

static __device__ __forceinline__ unsigned short f2bf(float f) {
  union { float f; unsigned int u; } v; v.f = f;
  unsigned int r = v.u + 0x7fffu + ((v.u >> 16) & 1u);
  return (unsigned short)(r >> 16);
}

// ---------------- cast fp32 -> bf16, vectorized x4 ----------------
__global__ void cast_kernel(const float* __restrict__ in,
                            unsigned short* __restrict__ out, int n4) {
  int i = blockIdx.x * blockDim.x + threadIdx.x;
  if (i < n4) {
    float4 v = ((const float4*)in)[i];
    ushort4 o;
    o.x = f2bf(v.x); o.y = f2bf(v.y); o.z = f2bf(v.z); o.w = f2bf(v.w);
    ((ushort4*)out)[i] = o;
  }
}

// ---------------- cast + transpose: in [R][C] fp32 -> out [C][R] bf16 -------
__global__ __launch_bounds__(256) void cast_transpose(
    const float* __restrict__ in, unsigned short* __restrict__ out,
    int R, int C) {
  const int r0 = blockIdx.y * 64, c0 = blockIdx.x * 64;
  const int tid = threadIdx.x;
  __shared__ float tl[64][65];
  const int rr = tid >> 4, cc = (tid & 15) * 4;
#pragma unroll
  for (int i = 0; i < 4; ++i) {
    int row = rr + i * 16;
    float4 v = *(const float4*)(in + (size_t)(r0 + row) * C + c0 + cc);
    tl[row][cc] = v.x; tl[row][cc + 1] = v.y;
    tl[row][cc + 2] = v.z; tl[row][cc + 3] = v.w;
  }
  __syncthreads();
  const int cl = tid >> 2, rbase = (tid & 3) * 16;
  unsigned short o[16];
#pragma unroll
  for (int j = 0; j < 16; ++j) o[j] = f2bf(tl[rbase + j][cl]);
  unsigned short* dst = out + (size_t)(c0 + cl) * R + r0 + rbase;
  *(uint4*)dst = *(uint4*)o;
  *(uint4*)(dst + 8) = *(uint4*)(o + 8);
}

// ---------------- GEMM1: QKV = Xb @ WqkvT^T + bqkv, scatter -----------------
// Qt[bh][d][t] (packed, 0.5*log2e folded), Kc[bh][t][d], Vt[bh][d][t].
__global__ __launch_bounds__(256) void gemm_qkv(
    const unsigned short* __restrict__ A,
    const unsigned short* __restrict__ Bt,
    const float* __restrict__ bias,
    unsigned short* __restrict__ Qt,
    unsigned short* __restrict__ Kc,
    unsigned short* __restrict__ Vt) {
  const int K = 1024;
  const int m0 = blockIdx.y * 128, n0 = blockIdx.x * 128;
  const int tid = threadIdx.x, w = tid >> 6, l = tid & 63;
  const int l16 = l & 15, lq = l >> 4;
  const int wm = w >> 1, wn = w & 1;
  const int which = n0 >> 10;

  __shared__ unsigned short As[128 * 64];
  __shared__ unsigned short Bs[128 * 64];

  floatx4 acc[4][4] = {};

  int sA[4], sB[4];
  unsigned ldso[4];
#pragma unroll
  for (int j = 0; j < 4; ++j) {
    int s = j * 256 + tid;
    int row = s >> 3, blk = (s & 7) ^ (row & 7);
    sA[j] = (m0 + row) * K + blk * 8;
    sB[j] = (n0 + row) * K + blk * 8;
    ldso[j] = (unsigned)(j * 256 + w * 64) * 8;
  }

  if (which != 1) {
    for (int k0 = 0; k0 < K; k0 += 64) {
      __syncthreads();
#pragma unroll
      for (int j = 0; j < 4; ++j) {
        GLD16(A + sA[j] + k0, As + ldso[j]);
        GLD16(Bt + sB[j] + k0, Bs + ldso[j]);
      }
      __syncthreads();
#pragma unroll
      for (int kk = 0; kk < 2; ++kk) {
        bf16x8 af[4], bf[4];
#pragma unroll
        for (int mi = 0; mi < 4; ++mi) {
          int row = wm * 64 + mi * 16 + l16;
          int blk = (kk * 4 + lq) ^ (l16 & 7);
          af[mi] = *(const bf16x8*)(As + row * 64 + blk * 8);
        }
#pragma unroll
        for (int ni = 0; ni < 4; ++ni) {
          int row = wn * 64 + ni * 16 + l16;
          int blk = (kk * 4 + lq) ^ (l16 & 7);
          bf[ni] = *(const bf16x8*)(Bs + row * 64 + blk * 8);
        }
#pragma unroll
        for (int ni = 0; ni < 4; ++ni)
#pragma unroll
          for (int mi = 0; mi < 4; ++mi)
            acc[mi][ni] = MFMA16(af[mi], bf[ni], acc[mi][ni], 0, 0, 0);
      }
    }
    float bv[4];
#pragma unroll
    for (int ni = 0; ni < 4; ++ni) bv[ni] = bias[n0 + wn * 64 + ni * 16 + l16];
#pragma unroll
    for (int mi = 0; mi < 4; ++mi) {
#pragma unroll
      for (int ni = 0; ni < 4; ++ni) {
        int col = n0 + wn * 64 + ni * 16 + l16;
        int c1 = col & 1023;
        int h = c1 >> 6, dd = c1 & 63;
        int row0 = m0 + wm * 64 + mi * 16 + lq * 4;
        int bb = row0 >> 11, tt0 = row0 & 2047;
        size_t bh = (size_t)(bb * 16 + h);
        if (which == 2) {
          floatx4 vv = acc[mi][ni] + bv[ni];
          *(bf16x4*)(Vt + (bh * 64 + dd) * 2048 + tt0) =
              __builtin_convertvector(vv, bf16x4);
        } else {
          floatx4 vv = (acc[mi][ni] + bv[ni]) * 0.7213475204444817f;
          *(bf16x4*)(Qt + (bh * 64 + dd) * 2048 + tt0) =
              __builtin_convertvector(vv, bf16x4);
        }
      }
    }
  } else {
    for (int k0 = 0; k0 < K; k0 += 64) {
      __syncthreads();
#pragma unroll
      for (int j = 0; j < 4; ++j) {
        GLD16(A + sA[j] + k0, As + ldso[j]);
        GLD16(Bt + sB[j] + k0, Bs + ldso[j]);
      }
      __syncthreads();
#pragma unroll
      for (int kk = 0; kk < 2; ++kk) {
        bf16x8 af[4], bf[4];
#pragma unroll
        for (int mi = 0; mi < 4; ++mi) {
          int row = wm * 64 + mi * 16 + l16;
          int blk = (kk * 4 + lq) ^ (l16 & 7);
          af[mi] = *(const bf16x8*)(As + row * 64 + blk * 8);
        }
#pragma unroll
        for (int ni = 0; ni < 4; ++ni) {
          int row = wn * 64 + ni * 16 + l16;
          int blk = (kk * 4 + lq) ^ (l16 & 7);
          bf[ni] = *(const bf16x8*)(Bs + row * 64 + blk * 8);
        }
#pragma unroll
        for (int ni = 0; ni < 4; ++ni)
#pragma unroll
          for (int mi = 0; mi < 4; ++mi)
            acc[mi][ni] = MFMA16(bf[ni], af[mi], acc[mi][ni], 0, 0, 0);
      }
    }
#pragma unroll
    for (int mi = 0; mi < 4; ++mi) {
      int t_g = m0 + wm * 64 + mi * 16 + l16;
      int bb = t_g >> 11, tt = t_g & 2047;
#pragma unroll
      for (int ni = 0; ni < 4; ++ni) {
        int col0 = n0 + wn * 64 + ni * 16 + lq * 4;
        floatx4 bv = *(const floatx4*)(bias + col0);
        floatx4 vv = acc[mi][ni] + bv;
        int h = (col0 & 1023) >> 6, dd0 = col0 & 63;
        size_t bh = (size_t)(bb * 16 + h);
        *(bf16x4*)(Kc + (bh * 2048 + tt) * 64 + dd0) =
            __builtin_convertvector(vv, bf16x4);
      }
    }
  }
}

// ---------------- attention: K/V direct global->VGPR, ZERO barriers --------
// Per-wave: 32 q. K double-buffered one step ahead; V loaded at step top,
// consumed after S+softmax. Only LDS use: per-wave P^T round-trip (swizzled).
#define LOADK(KF, KT)                                                         \
  do {                                                                        \
    _Pragma("unroll") for (int ct_ = 0; ct_ < 4; ++ct_)                       \
        _Pragma("unroll") for (int c2_ = 0; c2_ < 2; ++c2_)                   \
            KF[ct_][c2_] = *(const bf16x8*)(kb + ((KT) + ct_ * 16 + l16) * 64 \
                                            + c2_ * 32 + lq * 8);             \
  } while (0)

#define LOADV(VF, KT)                                                         \
  do {                                                                        \
    _Pragma("unroll") for (int dt_ = 0; dt_ < 4; ++dt_)                       \
        _Pragma("unroll") for (int c2_ = 0; c2_ < 2; ++c2_)                   \
            VF[dt_][c2_] = *(const bf16x8*)(vb + (dt_ * 16 + l16) * 2048      \
                                            + (KT) + c2_ * 32 + lq * 8);      \
  } while (0)

#define STEP(KF, KT)                                                          \
  do {                                                                        \
    LOADV(vf, KT);                                                            \
    floatx4 st_[2][4];                                                        \
    _Pragma("unroll") for (int ct = 0; ct < 4; ++ct) {                        \
      _Pragma("unroll") for (int qs = 0; qs < 2; ++qs) {                      \
        floatx4 z = {};                                                       \
        z = MFMA16(KF[ct][0], qf[qs][0], z, 0, 0, 0);                         \
        z = MFMA16(KF[ct][1], qf[qs][1], z, 0, 0, 0);                         \
        st_[qs][ct] = z;                                                      \
      }                                                                       \
    }                                                                         \
    _Pragma("unroll") for (int qs = 0; qs < 2; ++qs) {                        \
      _Pragma("unroll") for (int ct = 0; ct < 4; ++ct) {                      \
        floatx4 pv;                                                           \
        pv[0] = __builtin_amdgcn_exp2f(st_[qs][ct][0]);                       \
        pv[1] = __builtin_amdgcn_exp2f(st_[qs][ct][1]);                       \
        pv[2] = __builtin_amdgcn_exp2f(st_[qs][ct][2]);                       \
        pv[3] = __builtin_amdgcn_exp2f(st_[qs][ct][3]);                       \
        l_lane[qs] += (pv[0] + pv[1]) + (pv[2] + pv[3]);                      \
        bf16x4 pb = __builtin_convertvector(pv, bf16x4);                      \
        int blk16 = (ct * 2 + (lq >> 1)) ^ (l16 & 7);                         \
        *(bf16x4*)(pw + (qs * 16 + l16) * 64 + blk16 * 8 + (lq & 1) * 4) =    \
            pb;                                                               \
      }                                                                       \
    }                                                                         \
    bf16x8 pf_[2][2];                                                         \
    _Pragma("unroll") for (int qs = 0; qs < 2; ++qs)                          \
        _Pragma("unroll") for (int c2 = 0; c2 < 2; ++c2) {                    \
      int blkr = (c2 * 4 + lq) ^ (l16 & 7);                                   \
      pf_[qs][c2] = *(const bf16x8*)(pw + (qs * 16 + l16) * 64 + blkr * 8);   \
    }                                                                         \
    _Pragma("unroll") for (int dt = 0; dt < 4; ++dt)                          \
        _Pragma("unroll") for (int qs = 0; qs < 2; ++qs) {                    \
      o_acc[dt][qs] = MFMA16(vf[dt][0], pf_[qs][0], o_acc[dt][qs], 0, 0, 0);  \
      o_acc[dt][qs] = MFMA16(vf[dt][1], pf_[qs][1], o_acc[dt][qs], 0, 0, 0);  \
    }                                                                         \
  } while (0)

__global__ __launch_bounds__(256, 2) void attn_kernel(
    const unsigned short* __restrict__ Qt,
    const unsigned short* __restrict__ Kc,
    const unsigned short* __restrict__ Vt,
    unsigned short* __restrict__ AO) {
  const int T = 2048;
  const int bh = blockIdx.y, q0 = blockIdx.x * 128;
  const int tid = threadIdx.x, w = tid >> 6, l = tid & 63;
  const int l16 = l & 15, lq = l >> 4;

  __shared__ unsigned short Ps[4][32 * 64];  // 16 KB total, per-wave regions

  // Q fragments from Qt[bh][d][t] (scale+log2e pre-folded): one-time loads
  bf16x8 qf[2][2];
  {
    const unsigned short* qtb = Qt + (size_t)bh * 64 * 2048 + q0 + w * 32;
#pragma unroll
    for (int qs = 0; qs < 2; ++qs) {
      int t = qs * 16 + l16;
#pragma unroll
      for (int c2 = 0; c2 < 2; ++c2)
#pragma unroll
        for (int j = 0; j < 8; ++j) {
          int d = c2 * 32 + lq * 8 + j;
          qf[qs][c2][j] = ((const __bf16*)qtb)[(size_t)d * 2048 + t];
        }
    }
  }

  float l_lane[2] = {0.f, 0.f};
  floatx4 o_acc[4][2] = {};
  const unsigned short* kb = Kc + (size_t)bh * T * 64;
  const unsigned short* vb = Vt + (size_t)bh * 64 * T;
  unsigned short* pw = Ps[w];

  bf16x8 kfA[4][2], kfB[4][2], vf[4][2];
  LOADK(kfA, 0);
  for (int it = 0; it < 32; it += 2) {
    LOADK(kfB, (it + 1) * 64);     // prefetch K for step B (one step ahead)
    STEP(kfA, it * 64);
    if (it + 2 < 32) {
      LOADK(kfA, (it + 2) * 64);   // prefetch K for next step A
      STEP(kfB, (it + 1) * 64);
    } else {
      STEP(kfB, (it + 1) * 64);
    }
  }

  const int b = bh >> 4, h = bh & 15;
#pragma unroll
  for (int qs = 0; qs < 2; ++qs) {
    float ls = l_lane[qs];
    ls += __shfl_xor(ls, 16, 64);
    ls += __shfl_xor(ls, 32, 64);
    float inv = 1.0f / ls;
    int t = q0 + w * 32 + qs * 16 + l16;
#pragma unroll
    for (int dt = 0; dt < 4; ++dt) {
      floatx4 ov = o_acc[dt][qs] * inv;
      bf16x4 ob = __builtin_convertvector(ov, bf16x4);
      *(bf16x4*)(AO + ((size_t)b * 2048 + t) * 1024 + h * 64 + dt * 16 +
                 lq * 4) = ob;
    }
  }
}

// ---------------- GEMM2: out = AO @ WprojT^T + bproj, swapped -> float4 -----
__global__ __launch_bounds__(256) void gemm_proj(
    const unsigned short* __restrict__ A,
    const unsigned short* __restrict__ Bt,
    const float* __restrict__ bias,
    float* __restrict__ out) {
  const int K = 1024, N = 1024;
  const int m0 = blockIdx.y * 128, n0 = blockIdx.x * 64;
  const int tid = threadIdx.x, w = tid >> 6, l = tid & 63;
  const int l16 = l & 15, lq = l >> 4;

  __shared__ unsigned short As[128 * 64];
  __shared__ unsigned short Bs[64 * 64];

  floatx4 acc[2][4] = {};

  int sA[4], sB[2];
  unsigned ldsoA[4], ldsoB[2];
#pragma unroll
  for (int j = 0; j < 4; ++j) {
    int s = j * 256 + tid;
    int row = s >> 3, blk = (s & 7) ^ (row & 7);
    sA[j] = (m0 + row) * K + blk * 8;
    ldsoA[j] = (unsigned)(j * 256 + w * 64) * 8;
  }
#pragma unroll
  for (int j = 0; j < 2; ++j) {
    int s = j * 256 + tid;
    int row = s >> 3, blk = (s & 7) ^ (row & 7);
    sB[j] = (n0 + row) * K + blk * 8;
    ldsoB[j] = (unsigned)(j * 256 + w * 64) * 8;
  }

  for (int k0 = 0; k0 < K; k0 += 64) {
    __syncthreads();
#pragma unroll
    for (int j = 0; j < 4; ++j) GLD16(A + sA[j] + k0, As + ldsoA[j]);
#pragma unroll
    for (int j = 0; j < 2; ++j) GLD16(Bt + sB[j] + k0, Bs + ldsoB[j]);
    __syncthreads();
#pragma unroll
    for (int kk = 0; kk < 2; ++kk) {
      bf16x8 af[2], bf[4];
#pragma unroll
      for (int mi = 0; mi < 2; ++mi) {
        int row = w * 32 + mi * 16 + l16;
        int blk = (kk * 4 + lq) ^ (l16 & 7);
        af[mi] = *(const bf16x8*)(As + row * 64 + blk * 8);
      }
#pragma unroll
      for (int ni = 0; ni < 4; ++ni) {
        int row = ni * 16 + l16;
        int blk = (kk * 4 + lq) ^ (l16 & 7);
        bf[ni] = *(const bf16x8*)(Bs + row * 64 + blk * 8);
      }
#pragma unroll
      for (int ni = 0; ni < 4; ++ni)
#pragma unroll
        for (int mi = 0; mi < 2; ++mi)
          acc[mi][ni] = MFMA16(bf[ni], af[mi], acc[mi][ni], 0, 0, 0);
    }
  }

#pragma unroll
  for (int mi = 0; mi < 2; ++mi) {
    int t = m0 + w * 32 + mi * 16 + l16;
#pragma unroll
    for (int ni = 0; ni < 4; ++ni) {
      int col0 = n0 + ni * 16 + lq * 4;
      floatx4 bv = *(const floatx4*)(bias + col0);
      *(floatx4*)(out + (size_t)t * N + col0) = acc[mi][ni] + bv;
    }
  }
}

extern "C" void kernel_launch(void* const* d_in, const int* in_sizes, int n_in,
                              void* d_out, int out_size, void* d_ws,
                              size_t ws_size, hipStream_t stream) {
  const float* x     = (const float*)d_in[0];
  const float* Wqkv  = (const float*)d_in[1];
  const float* bqkv  = (const float*)d_in[2];
  const float* Wproj = (const float*)d_in[3];
  const float* bproj = (const float*)d_in[4];
  float* out = (float*)d_out;

  unsigned short* Xb     = (unsigned short*)d_ws;  // 4096x1024
  unsigned short* Wqkvt  = Xb + 4194304;           // 3072x1024 (transposed)
  unsigned short* Wprojt = Wqkvt + 3145728;        // 1024x1024 (transposed)
  unsigned short* Qtb    = Wprojt + 1048576;       // 32x64x2048 (pre-scaled)
  unsigned short* Kb     = Qtb + 4194304;          // 32x2048x64
  unsigned short* Vtb    = Kb + 4194304;           // 32x64x2048
  unsigned short* AOb    = Vtb + 4194304;          // 4096x1024

  cast_kernel<<<4096, 256, 0, stream>>>(x, Xb, 1048576);
  cast_transpose<<<dim3(48, 16), 256, 0, stream>>>(Wqkv, Wqkvt, 1024, 3072);
  cast_transpose<<<dim3(16, 16), 256, 0, stream>>>(Wproj, Wprojt, 1024, 1024);

  gemm_qkv<<<dim3(24, 32), 256, 0, stream>>>(Xb, Wqkvt, bqkv, Qtb, Kb, Vtb);
  attn_kernel<<<dim3(16, 32), 256, 0, stream>>>(Qtb, Kb, Vtb, AOb);
  gemm_proj<<<dim3(16, 32), 256, 0, stream>>>(AOb, Wprojt, bproj, out);
}

// Round 7
// 195.694 us; speedup vs baseline: 1.3457x; 1.3457x over previous
//
#include <hip/hip_runtime.h>

typedef float floatx4 __attribute__((ext_vector_type(4)));
typedef __bf16 bf16x8 __attribute__((ext_vector_type(8)));
typedef __bf16 bf16x4 __attribute__((ext_vector_type(4)));

#define MFMA16 __builtin_amdgcn_mfma_f32_16x16x32_bf16

typedef const __attribute__((address_space(1))) void* gas_t;
typedef __attribute__((address_space(3))) void* las_t;
#define GLD16(g, l) __builtin_amdgcn_global_load_lds((gas_t)(g), (las_t)(l), 16, 0, 0)

static __device__ __forceinline__ unsigned short f2bf(float f) {
  union { float f; unsigned int u; } v; v.f = f;
  unsigned int r = v.u + 0x7fffu + ((v.u >> 16) & 1u);
  return (unsigned short)(r >> 16);
}

// ---------------- fused prologue: cast x + transpose Wqkv + transpose Wproj -
static __device__ __forceinline__ void cast_transpose_tile(
    const float* __restrict__ in, unsigned short* __restrict__ out,
    int R, int C, int bx, int by) {
  const int r0 = by * 64, c0 = bx * 64;
  const int tid = threadIdx.x;
  __shared__ float tl[64][65];
  const int rr = tid >> 4, cc = (tid & 15) * 4;
#pragma unroll
  for (int i = 0; i < 4; ++i) {
    int row = rr + i * 16;
    float4 v = *(const float4*)(in + (size_t)(r0 + row) * C + c0 + cc);
    tl[row][cc] = v.x; tl[row][cc + 1] = v.y;
    tl[row][cc + 2] = v.z; tl[row][cc + 3] = v.w;
  }
  __syncthreads();
  const int cl = tid >> 2, rbase = (tid & 3) * 16;
  unsigned short o[16];
#pragma unroll
  for (int j = 0; j < 16; ++j) o[j] = f2bf(tl[rbase + j][cl]);
  unsigned short* dst = out + (size_t)(c0 + cl) * R + r0 + rbase;
  *(uint4*)dst = *(uint4*)o;
  *(uint4*)(dst + 8) = *(uint4*)(o + 8);
}

__global__ __launch_bounds__(256) void prologue_kernel(
    const float* __restrict__ x, unsigned short* __restrict__ Xb,
    const float* __restrict__ Wqkv, unsigned short* __restrict__ Wqkvt,
    const float* __restrict__ Wproj, unsigned short* __restrict__ Wprojt) {
  const int bid = blockIdx.x;
  if (bid < 4096) {
    int i = bid * 256 + threadIdx.x;
    float4 v = ((const float4*)x)[i];
    ushort4 o;
    o.x = f2bf(v.x); o.y = f2bf(v.y); o.z = f2bf(v.z); o.w = f2bf(v.w);
    ((ushort4*)Xb)[i] = o;
  } else if (bid < 4096 + 768) {
    int b2 = bid - 4096;
    cast_transpose_tile(Wqkv, Wqkvt, 1024, 3072, b2 % 48, b2 / 48);
  } else {
    int b3 = bid - 4096 - 768;
    cast_transpose_tile(Wproj, Wprojt, 1024, 1024, b3 % 16, b3 / 16);
  }
}

// ---------------- GEMM1: QKV = Xb @ WqkvT^T + bqkv, scatter -----------------
// Q[bh][t][d] (row-major, 0.5*log2e folded), Kc[bh][t][d], Vt[bh][d][t].
// Q/K blocks use swapped MFMA operands -> lane holds 4 consecutive d.
__global__ __launch_bounds__(256) void gemm_qkv(
    const unsigned short* __restrict__ A,
    const unsigned short* __restrict__ Bt,
    const float* __restrict__ bias,
    unsigned short* __restrict__ Q,
    unsigned short* __restrict__ Kc,
    unsigned short* __restrict__ Vt) {
  const int K = 1024;
  const int m0 = blockIdx.y * 128, n0 = blockIdx.x * 128;
  const int tid = threadIdx.x, w = tid >> 6, l = tid & 63;
  const int l16 = l & 15, lq = l >> 4;
  const int wm = w >> 1, wn = w & 1;
  const int which = n0 >> 10;

  __shared__ unsigned short As[128 * 64];
  __shared__ unsigned short Bs[128 * 64];

  floatx4 acc[4][4] = {};

  int sA[4], sB[4];
  unsigned ldso[4];
#pragma unroll
  for (int j = 0; j < 4; ++j) {
    int s = j * 256 + tid;
    int row = s >> 3, blk = (s & 7) ^ (row & 7);
    sA[j] = (m0 + row) * K + blk * 8;
    sB[j] = (n0 + row) * K + blk * 8;
    ldso[j] = (unsigned)(j * 256 + w * 64) * 8;
  }

  if (which == 2) {
    for (int k0 = 0; k0 < K; k0 += 64) {
      __syncthreads();
#pragma unroll
      for (int j = 0; j < 4; ++j) {
        GLD16(A + sA[j] + k0, As + ldso[j]);
        GLD16(Bt + sB[j] + k0, Bs + ldso[j]);
      }
      __syncthreads();
#pragma unroll
      for (int kk = 0; kk < 2; ++kk) {
        bf16x8 af[4], bf[4];
#pragma unroll
        for (int mi = 0; mi < 4; ++mi) {
          int row = wm * 64 + mi * 16 + l16;
          int blk = (kk * 4 + lq) ^ (l16 & 7);
          af[mi] = *(const bf16x8*)(As + row * 64 + blk * 8);
        }
#pragma unroll
        for (int ni = 0; ni < 4; ++ni) {
          int row = wn * 64 + ni * 16 + l16;
          int blk = (kk * 4 + lq) ^ (l16 & 7);
          bf[ni] = *(const bf16x8*)(Bs + row * 64 + blk * 8);
        }
#pragma unroll
        for (int ni = 0; ni < 4; ++ni)
#pragma unroll
          for (int mi = 0; mi < 4; ++mi)
            acc[mi][ni] = MFMA16(af[mi], bf[ni], acc[mi][ni], 0, 0, 0);
      }
    }
    float bv[4];
#pragma unroll
    for (int ni = 0; ni < 4; ++ni) bv[ni] = bias[n0 + wn * 64 + ni * 16 + l16];
#pragma unroll
    for (int mi = 0; mi < 4; ++mi) {
#pragma unroll
      for (int ni = 0; ni < 4; ++ni) {
        int col = n0 + wn * 64 + ni * 16 + l16;
        int c1 = col & 1023;
        int h = c1 >> 6, dd = c1 & 63;
        int row0 = m0 + wm * 64 + mi * 16 + lq * 4;
        int bb = row0 >> 11, tt0 = row0 & 2047;
        size_t bh = (size_t)(bb * 16 + h);
        floatx4 vv = acc[mi][ni] + bv[ni];
        *(bf16x4*)(Vt + (bh * 64 + dd) * 2048 + tt0) =
            __builtin_convertvector(vv, bf16x4);
      }
    }
  } else {
    for (int k0 = 0; k0 < K; k0 += 64) {
      __syncthreads();
#pragma unroll
      for (int j = 0; j < 4; ++j) {
        GLD16(A + sA[j] + k0, As + ldso[j]);
        GLD16(Bt + sB[j] + k0, Bs + ldso[j]);
      }
      __syncthreads();
#pragma unroll
      for (int kk = 0; kk < 2; ++kk) {
        bf16x8 af[4], bf[4];
#pragma unroll
        for (int mi = 0; mi < 4; ++mi) {
          int row = wm * 64 + mi * 16 + l16;
          int blk = (kk * 4 + lq) ^ (l16 & 7);
          af[mi] = *(const bf16x8*)(As + row * 64 + blk * 8);
        }
#pragma unroll
        for (int ni = 0; ni < 4; ++ni) {
          int row = wn * 64 + ni * 16 + l16;
          int blk = (kk * 4 + lq) ^ (l16 & 7);
          bf[ni] = *(const bf16x8*)(Bs + row * 64 + blk * 8);
        }
#pragma unroll
        for (int ni = 0; ni < 4; ++ni)
#pragma unroll
          for (int mi = 0; mi < 4; ++mi)
            acc[mi][ni] = MFMA16(bf[ni], af[mi], acc[mi][ni], 0, 0, 0);
      }
    }
    const float sc = (which == 0) ? 0.7213475204444817f : 1.0f;
    unsigned short* dst = (which == 0) ? Q : Kc;
#pragma unroll
    for (int mi = 0; mi < 4; ++mi) {
      int t_g = m0 + wm * 64 + mi * 16 + l16;
      int bb = t_g >> 11, tt = t_g & 2047;
#pragma unroll
      for (int ni = 0; ni < 4; ++ni) {
        int col0 = n0 + wn * 64 + ni * 16 + lq * 4;
        floatx4 bv = *(const floatx4*)(bias + col0);
        floatx4 vv = (acc[mi][ni] + bv) * sc;
        int h = (col0 & 1023) >> 6, dd0 = col0 & 63;
        size_t bh = (size_t)(bb * 16 + h);
        *(bf16x4*)(dst + (bh * 2048 + tt) * 64 + dd0) =
            __builtin_convertvector(vv, bf16x4);
      }
    }
  }
}

// ---------------- attention: 64 q/wave, intra-block k-split, 8 waves --------
// Block: 512 thr = 4 q-waves x 2 k-halves over 256 q. No-max softmax makes
// k-partials additive; combine via LDS at the end (reuses K/V buffers).
__global__ __launch_bounds__(512, 2) void attn_kernel(
    const unsigned short* __restrict__ Q,
    const unsigned short* __restrict__ Kc,
    const unsigned short* __restrict__ Vt,
    unsigned short* __restrict__ AO) {
  const int T = 2048;
  const int bh = blockIdx.y, q0 = blockIdx.x * 256;
  const int tid = threadIdx.x, w = tid >> 6, l = tid & 63;
  const int l16 = l & 15, lq = l >> 4;
  const int kh = w >> 2, wq = w & 3;     // k-half, q-wave
  const int h256 = tid & 255;

  __shared__ unsigned short KVs[2][2][2][4096];  // [K/V][kh][buf] 64 KB
  __shared__ unsigned short Ps[8][64 * 64];      // per-wave P^T, 64 KB
  __shared__ float Lx[4][4][64];                 // l exchange, 4 KB

  // Q fragments (row-major Q[bh][t][d], scale+log2e pre-folded): 16 b128 loads
  bf16x8 qf[4][2];
  {
    const unsigned short* qb = Q + ((size_t)bh * T + q0 + wq * 64) * 64;
#pragma unroll
    for (int qs = 0; qs < 4; ++qs) {
      const unsigned short* qr = qb + (qs * 16 + l16) * 64;
      qf[qs][0] = *(const bf16x8*)(qr + lq * 8);
      qf[qs][1] = *(const bf16x8*)(qr + 32 + lq * 8);
    }
  }

  float l_lane[4] = {0.f, 0.f, 0.f, 0.f};
  floatx4 o_acc[4][4] = {};

  const unsigned short* kbase = Kc + (size_t)bh * T * 64;
  const unsigned short* vbase = Vt + (size_t)bh * 64 * T;
  int kro[2], vro[2];
  unsigned ldso[2];
#pragma unroll
  for (int j = 0; j < 2; ++j) {
    int s = j * 256 + h256;
    int row = s >> 3, blk = (s & 7) ^ (row & 7);
    kro[j] = row * 64 + blk * 8;   // + chunk*4096
    vro[j] = row * T + blk * 8;    // + chunk*64
    ldso[j] = (unsigned)(j * 256 + wq * 64) * 8;
  }

  const int swz0 = (0 + lq) ^ (l16 & 7);
  const int swz1 = (4 + lq) ^ (l16 & 7);
  unsigned short* pw = Ps[w];

  {
    int c0 = kh * 16;
#pragma unroll
    for (int j = 0; j < 2; ++j) {
      GLD16(kbase + c0 * 4096 + kro[j], &KVs[0][kh][0][ldso[j]]);
      GLD16(vbase + c0 * 64 + vro[j], &KVs[1][kh][0][ldso[j]]);
    }
  }

  for (int it = 0; it < 16; ++it) {
    __syncthreads();
    if (it + 1 < 16) {
      int cn = kh * 16 + it + 1, nb = (it + 1) & 1;
#pragma unroll
      for (int j = 0; j < 2; ++j) {
        GLD16(kbase + cn * 4096 + kro[j], &KVs[0][kh][nb][ldso[j]]);
        GLD16(vbase + cn * 64 + vro[j], &KVs[1][kh][nb][ldso[j]]);
      }
    }
    const unsigned short* kb = KVs[0][kh][it & 1];
    const unsigned short* vb = KVs[1][kh][it & 1];

    // K fragments once (reused by all 4 q-subtiles)
    bf16x8 kf[4][2];
#pragma unroll
    for (int ct = 0; ct < 4; ++ct) {
      const unsigned short* kr = kb + (ct * 16 + l16) * 64;
      kf[ct][0] = *(const bf16x8*)(kr + swz0 * 8);
      kf[ct][1] = *(const bf16x8*)(kr + swz1 * 8);
    }

    // S^T + softmax numerators, in qs-pairs (register pressure)
#pragma unroll
    for (int qp = 0; qp < 2; ++qp) {
      floatx4 st[2][4];
#pragma unroll
      for (int ct = 0; ct < 4; ++ct)
#pragma unroll
        for (int q2 = 0; q2 < 2; ++q2) {
          int qs = qp * 2 + q2;
          floatx4 z = {};
          z = MFMA16(kf[ct][0], qf[qs][0], z, 0, 0, 0);
          z = MFMA16(kf[ct][1], qf[qs][1], z, 0, 0, 0);
          st[q2][ct] = z;
        }
#pragma unroll
      for (int q2 = 0; q2 < 2; ++q2) {
        int qs = qp * 2 + q2;
#pragma unroll
        for (int ct = 0; ct < 4; ++ct) {
          floatx4 pv;
          pv[0] = __builtin_amdgcn_exp2f(st[q2][ct][0]);
          pv[1] = __builtin_amdgcn_exp2f(st[q2][ct][1]);
          pv[2] = __builtin_amdgcn_exp2f(st[q2][ct][2]);
          pv[3] = __builtin_amdgcn_exp2f(st[q2][ct][3]);
          l_lane[qs] += (pv[0] + pv[1]) + (pv[2] + pv[3]);
          bf16x4 pb = __builtin_convertvector(pv, bf16x4);
          int blk16 = (ct * 2 + (lq >> 1)) ^ (l16 & 7);
          *(bf16x4*)(pw + (qs * 16 + l16) * 64 + blk16 * 8 + (lq & 1) * 4) =
              pb;
        }
      }
    }

    // P^T B-fragments (intra-wave LDS round-trip)
    bf16x8 pf[4][2];
#pragma unroll
    for (int qs = 0; qs < 4; ++qs)
#pragma unroll
      for (int c2 = 0; c2 < 2; ++c2) {
        int blkr = (c2 * 4 + lq) ^ (l16 & 7);
        pf[qs][c2] = *(const bf16x8*)(pw + (qs * 16 + l16) * 64 + blkr * 8);
      }

    // O^T += V^T * P^T
#pragma unroll
    for (int dt = 0; dt < 4; ++dt) {
      const unsigned short* vr = vb + (dt * 16 + l16) * 64;
      bf16x8 vf0 = *(const bf16x8*)(vr + swz0 * 8);
      bf16x8 vf1 = *(const bf16x8*)(vr + swz1 * 8);
#pragma unroll
      for (int qs = 0; qs < 4; ++qs) {
        o_acc[dt][qs] = MFMA16(vf0, pf[qs][0], o_acc[dt][qs], 0, 0, 0);
        o_acc[dt][qs] = MFMA16(vf1, pf[qs][1], o_acc[dt][qs], 0, 0, 0);
      }
    }
  }

  // ---- combine the two k-halves ----
  __syncthreads();  // everyone done with K/V LDS; safe to reuse as exchange
  float* ex = (float*)&KVs[0][0][0][0];  // 64 KB = 4 waves x 16 KB
  if (kh == 1) {
    float* r = ex + wq * 4096;
#pragma unroll
    for (int dt = 0; dt < 4; ++dt)
#pragma unroll
      for (int qs = 0; qs < 4; ++qs)
        *(floatx4*)(r + ((dt * 4 + qs) * 64 + l) * 4) = o_acc[dt][qs];
#pragma unroll
    for (int qs = 0; qs < 4; ++qs) Lx[wq][qs][l] = l_lane[qs];
  }
  __syncthreads();
  if (kh == 0) {
    const float* r = ex + wq * 4096;
    const int b = bh >> 4, h = bh & 15;
#pragma unroll
    for (int qs = 0; qs < 4; ++qs) {
      float ls = l_lane[qs] + Lx[wq][qs][l];
      ls += __shfl_xor(ls, 16, 64);
      ls += __shfl_xor(ls, 32, 64);
      float inv = 1.0f / ls;
      int t = q0 + wq * 64 + qs * 16 + l16;
#pragma unroll
      for (int dt = 0; dt < 4; ++dt) {
        floatx4 ov = o_acc[dt][qs] +
                     *(const floatx4*)(r + ((dt * 4 + qs) * 64 + l) * 4);
        ov *= inv;
        bf16x4 ob = __builtin_convertvector(ov, bf16x4);
        *(bf16x4*)(AO + ((size_t)b * 2048 + t) * 1024 + h * 64 + dt * 16 +
                   lq * 4) = ob;
      }
    }
  }
}

// ---------------- GEMM2: out = AO @ WprojT^T + bproj, swapped -> float4 -----
__global__ __launch_bounds__(256) void gemm_proj(
    const unsigned short* __restrict__ A,
    const unsigned short* __restrict__ Bt,
    const float* __restrict__ bias,
    float* __restrict__ out) {
  const int K = 1024, N = 1024;
  const int m0 = blockIdx.y * 128, n0 = blockIdx.x * 64;
  const int tid = threadIdx.x, w = tid >> 6, l = tid & 63;
  const int l16 = l & 15, lq = l >> 4;

  __shared__ unsigned short As[128 * 64];
  __shared__ unsigned short Bs[64 * 64];

  floatx4 acc[2][4] = {};

  int sA[4], sB[2];
  unsigned ldsoA[4], ldsoB[2];
#pragma unroll
  for (int j = 0; j < 4; ++j) {
    int s = j * 256 + tid;
    int row = s >> 3, blk = (s & 7) ^ (row & 7);
    sA[j] = (m0 + row) * K + blk * 8;
    ldsoA[j] = (unsigned)(j * 256 + w * 64) * 8;
  }
#pragma unroll
  for (int j = 0; j < 2; ++j) {
    int s = j * 256 + tid;
    int row = s >> 3, blk = (s & 7) ^ (row & 7);
    sB[j] = (n0 + row) * K + blk * 8;
    ldsoB[j] = (unsigned)(j * 256 + w * 64) * 8;
  }

  for (int k0 = 0; k0 < K; k0 += 64) {
    __syncthreads();
#pragma unroll
    for (int j = 0; j < 4; ++j) GLD16(A + sA[j] + k0, As + ldsoA[j]);
#pragma unroll
    for (int j = 0; j < 2; ++j) GLD16(Bt + sB[j] + k0, Bs + ldsoB[j]);
    __syncthreads();
#pragma unroll
    for (int kk = 0; kk < 2; ++kk) {
      bf16x8 af[2], bf[4];
#pragma unroll
      for (int mi = 0; mi < 2; ++mi) {
        int row = w * 32 + mi * 16 + l16;
        int blk = (kk * 4 + lq) ^ (l16 & 7);
        af[mi] = *(const bf16x8*)(As + row * 64 + blk * 8);
      }
#pragma unroll
      for (int ni = 0; ni < 4; ++ni) {
        int row = ni * 16 + l16;
        int blk = (kk * 4 + lq) ^ (l16 & 7);
        bf[ni] = *(const bf16x8*)(Bs + row * 64 + blk * 8);
      }
#pragma unroll
      for (int ni = 0; ni < 4; ++ni)
#pragma unroll
        for (int mi = 0; mi < 2; ++mi)
          acc[mi][ni] = MFMA16(bf[ni], af[mi], acc[mi][ni], 0, 0, 0);
    }
  }

#pragma unroll
  for (int mi = 0; mi < 2; ++mi) {
    int t = m0 + w * 32 + mi * 16 + l16;
#pragma unroll
    for (int ni = 0; ni < 4; ++ni) {
      int col0 = n0 + ni * 16 + lq * 4;
      floatx4 bv = *(const floatx4*)(bias + col0);
      *(floatx4*)(out + (size_t)t * N + col0) = acc[mi][ni] + bv;
    }
  }
}

extern "C" void kernel_launch(void* const* d_in, const int* in_sizes, int n_in,
                              void* d_out, int out_size, void* d_ws,
                              size_t ws_size, hipStream_t stream) {
  const float* x     = (const float*)d_in[0];
  const float* Wqkv  = (const float*)d_in[1];
  const float* bqkv  = (const float*)d_in[2];
  const float* Wproj = (const float*)d_in[3];
  const float* bproj = (const float*)d_in[4];
  float* out = (float*)d_out;

  unsigned short* Xb     = (unsigned short*)d_ws;  // 4096x1024
  unsigned short* Wqkvt  = Xb + 4194304;           // 3072x1024 (transposed)
  unsigned short* Wprojt = Wqkvt + 3145728;        // 1024x1024 (transposed)
  unsigned short* Qb     = Wprojt + 1048576;       // 32x2048x64 (pre-scaled)
  unsigned short* Kb     = Qb + 4194304;           // 32x2048x64
  unsigned short* Vtb    = Kb + 4194304;           // 32x64x2048
  unsigned short* AOb    = Vtb + 4194304;          // 4096x1024

  prologue_kernel<<<5120, 256, 0, stream>>>(x, Xb, Wqkv, Wqkvt, Wproj, Wprojt);
  gemm_qkv<<<dim3(24, 32), 256, 0, stream>>>(Xb, Wqkvt, bqkv, Qb, Kb, Vtb);
  attn_kernel<<<dim3(8, 32), 512, 0, stream>>>(Qb, Kb, Vtb, AOb);
  gemm_proj<<<dim3(16, 32), 256, 0, stream>>>(AOb, Wprojt, bproj, out);
}

// Round 10
// 190.397 us; speedup vs baseline: 1.3831x; 1.0278x over previous
//
#include <hip/hip_runtime.h>

typedef float floatx4 __attribute__((ext_vector_type(4)));
typedef __bf16 bf16x8 __attribute__((ext_vector_type(8)));
typedef __bf16 bf16x4 __attribute__((ext_vector_type(4)));

#define MFMA16 __builtin_amdgcn_mfma_f32_16x16x32_bf16

typedef const __attribute__((address_space(1))) void* gas_t;
typedef __attribute__((address_space(3))) void* las_t;
#define GLD16(g, l) __builtin_amdgcn_global_load_lds((gas_t)(g), (las_t)(l), 16, 0, 0)

static __device__ __forceinline__ unsigned short f2bf(float f) {
  union { float f; unsigned int u; } v; v.f = f;
  unsigned int r = v.u + 0x7fffu + ((v.u >> 16) & 1u);
  return (unsigned short)(r >> 16);
}

// ---------------- fused prologue: cast x + transpose Wqkv + transpose Wproj -
static __device__ __forceinline__ void cast_transpose_tile(
    const float* __restrict__ in, unsigned short* __restrict__ out,
    int R, int C, int bx, int by) {
  const int r0 = by * 64, c0 = bx * 64;
  const int tid = threadIdx.x;
  __shared__ float tl[64][65];
  const int rr = tid >> 4, cc = (tid & 15) * 4;
#pragma unroll
  for (int i = 0; i < 4; ++i) {
    int row = rr + i * 16;
    float4 v = *(const float4*)(in + (size_t)(r0 + row) * C + c0 + cc);
    tl[row][cc] = v.x; tl[row][cc + 1] = v.y;
    tl[row][cc + 2] = v.z; tl[row][cc + 3] = v.w;
  }
  __syncthreads();
  const int cl = tid >> 2, rbase = (tid & 3) * 16;
  unsigned short o[16];
#pragma unroll
  for (int j = 0; j < 16; ++j) o[j] = f2bf(tl[rbase + j][cl]);
  unsigned short* dst = out + (size_t)(c0 + cl) * R + r0 + rbase;
  *(uint4*)dst = *(uint4*)o;
  *(uint4*)(dst + 8) = *(uint4*)(o + 8);
}

__global__ __launch_bounds__(256) void prologue_kernel(
    const float* __restrict__ x, unsigned short* __restrict__ Xb,
    const float* __restrict__ Wqkv, unsigned short* __restrict__ Wqkvt,
    const float* __restrict__ Wproj, unsigned short* __restrict__ Wprojt) {
  const int bid = blockIdx.x;
  if (bid < 4096) {
    int i = bid * 256 + threadIdx.x;
    float4 v = ((const float4*)x)[i];
    ushort4 o;
    o.x = f2bf(v.x); o.y = f2bf(v.y); o.z = f2bf(v.z); o.w = f2bf(v.w);
    ((ushort4*)Xb)[i] = o;
  } else if (bid < 4096 + 768) {
    int b2 = bid - 4096;
    cast_transpose_tile(Wqkv, Wqkvt, 1024, 3072, b2 % 48, b2 / 48);
  } else {
    int b3 = bid - 4096 - 768;
    cast_transpose_tile(Wproj, Wprojt, 1024, 1024, b3 % 16, b3 / 16);
  }
}

// ---------------- GEMM1: QKV = Xb @ WqkvT^T + bqkv, scatter -----------------
// Q[bh][t][d] (0.5*log2e folded), Kc[bh][t][d], Vt[bh][d][t].
// Epilogue bounces 64x64 wave-tiles through LDS (stride 72 = 144B, 16B-aligned
// rows) -> coalesced b128 stores. NOTE: t within batch = m0 & 2047 (batch is
// already encoded in bh) — raw m0 here was the round-8/9 corruption bug.
__global__ __launch_bounds__(256) void gemm_qkv(
    const unsigned short* __restrict__ A,
    const unsigned short* __restrict__ Bt,
    const float* __restrict__ bias,
    unsigned short* __restrict__ Q,
    unsigned short* __restrict__ Kc,
    unsigned short* __restrict__ Vt) {
  const int K = 1024;
  const int m0 = blockIdx.y * 128, n0 = blockIdx.x * 128;
  const int tid = threadIdx.x, w = tid >> 6, l = tid & 63;
  const int l16 = l & 15, lq = l >> 4;
  const int wm = w >> 1, wn = w & 1;
  const int which = n0 >> 10;

  __shared__ __align__(16) unsigned short SH[16384];
  unsigned short* As = SH;          // 128*64
  unsigned short* Bs = SH + 8192;   // 128*64

  floatx4 acc[4][4] = {};

  int sA[4], sB[4];
  unsigned ldso[4];
#pragma unroll
  for (int j = 0; j < 4; ++j) {
    int s = j * 256 + tid;
    int row = s >> 3, blk = (s & 7) ^ (row & 7);
    sA[j] = (m0 + row) * K + blk * 8;
    sB[j] = (n0 + row) * K + blk * 8;
    ldso[j] = (unsigned)(j * 256 + w * 64) * 8;
  }

  if (which == 2) {
    for (int k0 = 0; k0 < K; k0 += 64) {
      __syncthreads();
#pragma unroll
      for (int j = 0; j < 4; ++j) {
        GLD16(A + sA[j] + k0, As + ldso[j]);
        GLD16(Bt + sB[j] + k0, Bs + ldso[j]);
      }
      __syncthreads();
#pragma unroll
      for (int kk = 0; kk < 2; ++kk) {
        bf16x8 af[4], bf[4];
#pragma unroll
        for (int mi = 0; mi < 4; ++mi) {
          int row = wm * 64 + mi * 16 + l16;
          int blk = (kk * 4 + lq) ^ (l16 & 7);
          af[mi] = *(const bf16x8*)(As + row * 64 + blk * 8);
        }
#pragma unroll
        for (int ni = 0; ni < 4; ++ni) {
          int row = wn * 64 + ni * 16 + l16;
          int blk = (kk * 4 + lq) ^ (l16 & 7);
          bf[ni] = *(const bf16x8*)(Bs + row * 64 + blk * 8);
        }
#pragma unroll
        for (int ni = 0; ni < 4; ++ni)
#pragma unroll
          for (int mi = 0; mi < 4; ++mi)
            acc[mi][ni] = MFMA16(af[mi], bf[ni], acc[mi][ni], 0, 0, 0);
      }
    }
    // V: D[t(packed)][col]; bounce to [d][t] LDS, coalesced 128B-segment store
    float bv[4];
#pragma unroll
    for (int ni = 0; ni < 4; ++ni) bv[ni] = bias[n0 + wn * 64 + ni * 16 + l16];
    __syncthreads();
    unsigned short* E = SH + w * 2304;  // 32 rows x stride 72 (144B, 16B-mult)
    const int bh = (m0 >> 11) * 16 + ((n0 & 1023) >> 6) + wn;
    const int tt0 = (m0 & 2047) + wm * 64;
#pragma unroll
    for (int p = 0; p < 2; ++p) {
#pragma unroll
      for (int n2 = 0; n2 < 2; ++n2) {
        int ni = p * 2 + n2;
#pragma unroll
        for (int mi = 0; mi < 4; ++mi) {
          floatx4 vv = acc[mi][ni] + bv[ni];
          *(bf16x4*)(E + (n2 * 16 + l16) * 72 + mi * 16 + lq * 4) =
              __builtin_convertvector(vv, bf16x4);
        }
      }
#pragma unroll
      for (int s = 0; s < 4; ++s) {
        int dl = s * 8 + (l >> 3);
        bf16x8 vv = *(const bf16x8*)(E + dl * 72 + (l & 7) * 8);
        *(bf16x8*)(Vt + ((size_t)bh * 64 + p * 32 + dl) * 2048 + tt0 +
                   (l & 7) * 8) = vv;
      }
    }
  } else {
    for (int k0 = 0; k0 < K; k0 += 64) {
      __syncthreads();
#pragma unroll
      for (int j = 0; j < 4; ++j) {
        GLD16(A + sA[j] + k0, As + ldso[j]);
        GLD16(Bt + sB[j] + k0, Bs + ldso[j]);
      }
      __syncthreads();
#pragma unroll
      for (int kk = 0; kk < 2; ++kk) {
        bf16x8 af[4], bf[4];
#pragma unroll
        for (int mi = 0; mi < 4; ++mi) {
          int row = wm * 64 + mi * 16 + l16;
          int blk = (kk * 4 + lq) ^ (l16 & 7);
          af[mi] = *(const bf16x8*)(As + row * 64 + blk * 8);
        }
#pragma unroll
        for (int ni = 0; ni < 4; ++ni) {
          int row = wn * 64 + ni * 16 + l16;
          int blk = (kk * 4 + lq) ^ (l16 & 7);
          bf[ni] = *(const bf16x8*)(Bs + row * 64 + blk * 8);
        }
#pragma unroll
        for (int ni = 0; ni < 4; ++ni)
#pragma unroll
          for (int mi = 0; mi < 4; ++mi)
            acc[mi][ni] = MFMA16(bf[ni], af[mi], acc[mi][ni], 0, 0, 0);
      }
    }
    // Q/K: D[col(packed d)][t]; bounce to [t][d] LDS, coalesced 1KB stores
    const float sc = (which == 0) ? 0.7213475204444817f : 1.0f;
    unsigned short* dst = (which == 0) ? Q : Kc;
    __syncthreads();
    unsigned short* E = SH + w * 2304;
    const int bh = (m0 >> 11) * 16 + ((n0 & 1023) >> 6) + wn;
    const size_t gbase = ((size_t)bh * 2048 + (m0 & 2047) + wm * 64) * 64;
#pragma unroll
    for (int p = 0; p < 2; ++p) {
#pragma unroll
      for (int m2 = 0; m2 < 2; ++m2) {
        int mi = p * 2 + m2;
#pragma unroll
        for (int ni = 0; ni < 4; ++ni) {
          int col0 = n0 + wn * 64 + ni * 16 + lq * 4;
          floatx4 bv = *(const floatx4*)(bias + col0);
          floatx4 vv = (acc[mi][ni] + bv) * sc;
          *(bf16x4*)(E + (m2 * 16 + l16) * 72 + ni * 16 + lq * 4) =
              __builtin_convertvector(vv, bf16x4);
        }
      }
#pragma unroll
      for (int s = 0; s < 4; ++s) {
        int rl = s * 8 + (l >> 3);
        bf16x8 vv = *(const bf16x8*)(E + rl * 72 + (l & 7) * 8);
        *(bf16x8*)(dst + gbase + (size_t)(p * 32 + rl) * 64 + (l & 7) * 8) =
            vv;
      }
    }
  }
}

// ---------------- attention: 128 q/block, 2 q-waves x 2 k-halves, 2 blk/CU --
__global__ __launch_bounds__(256, 2) void attn_kernel(
    const unsigned short* __restrict__ Q,
    const unsigned short* __restrict__ Kc,
    const unsigned short* __restrict__ Vt,
    unsigned short* __restrict__ AO) {
  const int T = 2048;
  const int bh = blockIdx.y, q0 = blockIdx.x * 128;
  const int tid = threadIdx.x, w = tid >> 6, l = tid & 63;
  const int l16 = l & 15, lq = l >> 4;
  const int kh = w >> 1, wq = w & 1;  // k-half, q-wave
  const int h128 = tid & 127;

  __shared__ __align__(16) unsigned short KVs[2][2][2][4096];  // 64 KB
  __shared__ __align__(16) unsigned short Ps[4][1024];         // 2 KB/wave

  // Q fragments (row-major, scale+log2e pre-folded)
  bf16x8 qf[4][2];
  {
    const unsigned short* qb = Q + ((size_t)bh * T + q0 + wq * 64) * 64;
#pragma unroll
    for (int qs = 0; qs < 4; ++qs) {
      const unsigned short* qr = qb + (qs * 16 + l16) * 64;
      qf[qs][0] = *(const bf16x8*)(qr + lq * 8);
      qf[qs][1] = *(const bf16x8*)(qr + 32 + lq * 8);
    }
  }

  float l_lane[4] = {0.f, 0.f, 0.f, 0.f};
  floatx4 o_acc[4][4] = {};

  const unsigned short* kbase = Kc + (size_t)bh * T * 64;
  const unsigned short* vbase = Vt + (size_t)bh * 64 * T;
  int kro[4], vro[4];
  unsigned ldso[4];
#pragma unroll
  for (int j = 0; j < 4; ++j) {
    int s = j * 128 + h128;
    int row = s >> 3, blk = (s & 7) ^ (row & 7);
    kro[j] = row * 64 + blk * 8;   // + chunk*4096
    vro[j] = row * T + blk * 8;    // + chunk*64
    ldso[j] = (unsigned)(j * 128 + wq * 64) * 8;
  }

  const int swz0 = (0 + lq) ^ (l16 & 7);
  const int swz1 = (4 + lq) ^ (l16 & 7);
  unsigned short* pw = Ps[w];

  {
    int c0 = kh * 16;
#pragma unroll
    for (int j = 0; j < 4; ++j) {
      GLD16(kbase + c0 * 4096 + kro[j], &KVs[0][kh][0][ldso[j]]);
      GLD16(vbase + c0 * 64 + vro[j], &KVs[1][kh][0][ldso[j]]);
    }
  }

  for (int it = 0; it < 16; ++it) {
    __syncthreads();
    if (it + 1 < 16) {
      int cn = kh * 16 + it + 1, nb = (it + 1) & 1;
#pragma unroll
      for (int j = 0; j < 4; ++j) {
        GLD16(kbase + cn * 4096 + kro[j], &KVs[0][kh][nb][ldso[j]]);
        GLD16(vbase + cn * 64 + vro[j], &KVs[1][kh][nb][ldso[j]]);
      }
    }
    const unsigned short* kb = KVs[0][kh][it & 1];
    const unsigned short* vb = KVs[1][kh][it & 1];

    bf16x8 kf[4][2];
#pragma unroll
    for (int ct = 0; ct < 4; ++ct) {
      const unsigned short* kr = kb + (ct * 16 + l16) * 64;
      kf[ct][0] = *(const bf16x8*)(kr + swz0 * 8);
      kf[ct][1] = *(const bf16x8*)(kr + swz1 * 8);
    }

    // per-qs: S^T -> exp2 -> P write -> P read (2 KB LDS region reused)
    bf16x8 pf[4][2];
#pragma unroll
    for (int qs = 0; qs < 4; ++qs) {
      floatx4 st[4];
#pragma unroll
      for (int ct = 0; ct < 4; ++ct) {
        floatx4 z = {};
        z = MFMA16(kf[ct][0], qf[qs][0], z, 0, 0, 0);
        z = MFMA16(kf[ct][1], qf[qs][1], z, 0, 0, 0);
        st[ct] = z;
      }
#pragma unroll
      for (int ct = 0; ct < 4; ++ct) {
        floatx4 pv;
        pv[0] = __builtin_amdgcn_exp2f(st[ct][0]);
        pv[1] = __builtin_amdgcn_exp2f(st[ct][1]);
        pv[2] = __builtin_amdgcn_exp2f(st[ct][2]);
        pv[3] = __builtin_amdgcn_exp2f(st[ct][3]);
        l_lane[qs] += (pv[0] + pv[1]) + (pv[2] + pv[3]);
        bf16x4 pb = __builtin_convertvector(pv, bf16x4);
        int blk16 = (ct * 2 + (lq >> 1)) ^ (l16 & 7);
        *(bf16x4*)(pw + l16 * 64 + blk16 * 8 + (lq & 1) * 4) = pb;
      }
#pragma unroll
      for (int c2 = 0; c2 < 2; ++c2) {
        int blkr = (c2 * 4 + lq) ^ (l16 & 7);
        pf[qs][c2] = *(const bf16x8*)(pw + l16 * 64 + blkr * 8);
      }
    }

    // O^T += V^T * P^T
#pragma unroll
    for (int dt = 0; dt < 4; ++dt) {
      const unsigned short* vr = vb + (dt * 16 + l16) * 64;
      bf16x8 vf0 = *(const bf16x8*)(vr + swz0 * 8);
      bf16x8 vf1 = *(const bf16x8*)(vr + swz1 * 8);
#pragma unroll
      for (int qs = 0; qs < 4; ++qs) {
        o_acc[dt][qs] = MFMA16(vf0, pf[qs][0], o_acc[dt][qs], 0, 0, 0);
        o_acc[dt][qs] = MFMA16(vf1, pf[qs][1], o_acc[dt][qs], 0, 0, 0);
      }
    }
  }

  // ---- combine the two k-halves (no-max softmax partials are additive) ----
  __syncthreads();
  float* ex = (float*)&KVs[0][0][0][0];  // 2 x 16 KB regions (K buffers dead)
  float* Lx = (float*)&Ps[0][0];         // 2 x 4 qs x 64 lanes
  if (kh == 1) {
    float* r = ex + wq * 4096;
#pragma unroll
    for (int dt = 0; dt < 4; ++dt)
#pragma unroll
      for (int qs = 0; qs < 4; ++qs)
        *(floatx4*)(r + ((dt * 4 + qs) * 64 + l) * 4) = o_acc[dt][qs];
#pragma unroll
    for (int qs = 0; qs < 4; ++qs) Lx[(wq * 4 + qs) * 64 + l] = l_lane[qs];
  }
  __syncthreads();
  if (kh == 0) {
    const float* r = ex + wq * 4096;
    const int b = bh >> 4, h = bh & 15;
#pragma unroll
    for (int qs = 0; qs < 4; ++qs) {
      float ls = l_lane[qs] + Lx[(wq * 4 + qs) * 64 + l];
      ls += __shfl_xor(ls, 16, 64);
      ls += __shfl_xor(ls, 32, 64);
      float inv = 1.0f / ls;
      int t = q0 + wq * 64 + qs * 16 + l16;
#pragma unroll
      for (int dt = 0; dt < 4; ++dt) {
        floatx4 ov = o_acc[dt][qs] +
                     *(const floatx4*)(r + ((dt * 4 + qs) * 64 + l) * 4);
        ov *= inv;
        bf16x4 ob = __builtin_convertvector(ov, bf16x4);
        *(bf16x4*)(AO + ((size_t)b * 2048 + t) * 1024 + h * 64 + dt * 16 +
                   lq * 4) = ob;
      }
    }
  }
}

// ---------------- GEMM2: out = AO @ WprojT^T + bproj, swapped -> float4 -----
__global__ __launch_bounds__(256) void gemm_proj(
    const unsigned short* __restrict__ A,
    const unsigned short* __restrict__ Bt,
    const float* __restrict__ bias,
    float* __restrict__ out) {
  const int K = 1024, N = 1024;
  const int m0 = blockIdx.y * 128, n0 = blockIdx.x * 64;
  const int tid = threadIdx.x, w = tid >> 6, l = tid & 63;
  const int l16 = l & 15, lq = l >> 4;

  __shared__ __align__(16) unsigned short As[128 * 64];
  __shared__ __align__(16) unsigned short Bs[64 * 64];

  floatx4 acc[2][4] = {};

  int sA[4], sB[2];
  unsigned ldsoA[4], ldsoB[2];
#pragma unroll
  for (int j = 0; j < 4; ++j) {
    int s = j * 256 + tid;
    int row = s >> 3, blk = (s & 7) ^ (row & 7);
    sA[j] = (m0 + row) * K + blk * 8;
    ldsoA[j] = (unsigned)(j * 256 + w * 64) * 8;
  }
#pragma unroll
  for (int j = 0; j < 2; ++j) {
    int s = j * 256 + tid;
    int row = s >> 3, blk = (s & 7) ^ (row & 7);
    sB[j] = (n0 + row) * K + blk * 8;
    ldsoB[j] = (unsigned)(j * 256 + w * 64) * 8;
  }

  for (int k0 = 0; k0 < K; k0 += 64) {
    __syncthreads();
#pragma unroll
    for (int j = 0; j < 4; ++j) GLD16(A + sA[j] + k0, As + ldsoA[j]);
#pragma unroll
    for (int j = 0; j < 2; ++j) GLD16(Bt + sB[j] + k0, Bs + ldsoB[j]);
    __syncthreads();
#pragma unroll
    for (int kk = 0; kk < 2; ++kk) {
      bf16x8 af[2], bf[4];
#pragma unroll
      for (int mi = 0; mi < 2; ++mi) {
        int row = w * 32 + mi * 16 + l16;
        int blk = (kk * 4 + lq) ^ (l16 & 7);
        af[mi] = *(const bf16x8*)(As + row * 64 + blk * 8);
      }
#pragma unroll
      for (int ni = 0; ni < 4; ++ni) {
        int row = ni * 16 + l16;
        int blk = (kk * 4 + lq) ^ (l16 & 7);
        bf[ni] = *(const bf16x8*)(Bs + row * 64 + blk * 8);
      }
#pragma unroll
      for (int ni = 0; ni < 4; ++ni)
#pragma unroll
        for (int mi = 0; mi < 2; ++mi)
          acc[mi][ni] = MFMA16(bf[ni], af[mi], acc[mi][ni], 0, 0, 0);
    }
  }

#pragma unroll
  for (int mi = 0; mi < 2; ++mi) {
    int t = m0 + w * 32 + mi * 16 + l16;
#pragma unroll
    for (int ni = 0; ni < 4; ++ni) {
      int col0 = n0 + ni * 16 + lq * 4;
      floatx4 bv = *(const floatx4*)(bias + col0);
      *(floatx4*)(out + (size_t)t * N + col0) = acc[mi][ni] + bv;
    }
  }
}

extern "C" void kernel_launch(void* const* d_in, const int* in_sizes, int n_in,
                              void* d_out, int out_size, void* d_ws,
                              size_t ws_size, hipStream_t stream) {
  const float* x     = (const float*)d_in[0];
  const float* Wqkv  = (const float*)d_in[1];
  const float* bqkv  = (const float*)d_in[2];
  const float* Wproj = (const float*)d_in[3];
  const float* bproj = (const float*)d_in[4];
  float* out = (float*)d_out;

  unsigned short* Xb     = (unsigned short*)d_ws;  // 4096x1024
  unsigned short* Wqkvt  = Xb + 4194304;           // 3072x1024 (transposed)
  unsigned short* Wprojt = Wqkvt + 3145728;        // 1024x1024 (transposed)
  unsigned short* Qb     = Wprojt + 1048576;       // 32x2048x64 (pre-scaled)
  unsigned short* Kb     = Qb + 4194304;           // 32x2048x64
  unsigned short* Vtb    = Kb + 4194304;           // 32x64x2048
  unsigned short* AOb    = Vtb + 4194304;          // 4096x1024

  prologue_kernel<<<5120, 256, 0, stream>>>(x, Xb, Wqkv, Wqkvt, Wproj, Wprojt);
  gemm_qkv<<<dim3(24, 32), 256, 0, stream>>>(Xb, Wqkvt, bqkv, Qb, Kb, Vtb);
  attn_kernel<<<dim3(16, 32), 256, 0, stream>>>(Qb, Kb, Vtb, AOb);
  gemm_proj<<<dim3(16, 32), 256, 0, stream>>>(AOb, Wprojt, bproj, out);
}